// Round 8
// baseline (21.099 us; speedup 1.0000x reference)
//
#include <hip/hip_runtime.h>
#include <math.h>

#define NATOMS 32
#define NMOL   64
#define MAXP   466     // >= C(31,2)=465
#define RCRf 5.2f
#define RCAf 3.5f

// One block per (molecule n, center atom i). 384 threads (6 waves). 2 barriers.
// A (wave 0): per-atom dv/d/fc/species + ballot-compacted RCA neighbor list.
// B (all):    thread p < cnt decodes pair (jj<kk) in compacted space, computes
//             factorized record {f1[0..7], f2f[0..3]} + px, stores at slot=p
//             (UNSORTED -- no atomics, no histogram, no scan, no scatter).
// E:          tid<320 owns angular feature (px=tid>>5, a, z); branchless
//             predicated scan over ALL cnt records (3 LDS broadcasts + cndmask
//             + fma). tid 320..383 own the 64 radial features.
__global__ __launch_bounds__(384) void aev_kernel(const int* __restrict__ species,
                                                  const float* __restrict__ coords,
                                                  float* __restrict__ out) {
    const int bid = blockIdx.x;
    const int n = bid >> 5;
    const int i = bid & 31;
    const int tid = threadIdx.x;

    __shared__ float4 s_atom[NATOMS];            // dvx, dvy, dvz, d
    __shared__ float2 s_dfr[NATOMS];             // d, fcr (radial scan, 1 b64 read)
    __shared__ float  s_fca[NATOMS];
    __shared__ int    s_sp[NATOMS];
    __shared__ int    s_nbr[NATOMS];
    __shared__ int    s_nn;
    __shared__ __align__(16) float s_rec[MAXP*12];   // f1[0..7], f2f[0..3] per pair
    __shared__ int    s_px[MAXP];

    // ---------- phase A (wave 0) ----------
    if (tid < 64) {
        float fca_v = 0.f;
        if (tid < NATOMS) {
            const float* cb = coords + (size_t)n*NATOMS*3;
            float dx = cb[tid*3+0] - cb[i*3+0];
            float dy = cb[tid*3+1] - cb[i*3+1];
            float dz = cb[tid*3+2] - cb[i*3+2];
            float d2 = dx*dx + dy*dy + dz*dz;
            float d  = sqrtf(d2 > 0.f ? d2 : 1.f);   // ref's where(d2>0,d2,1) guard
            bool self = (tid == i);
            float fr = (!self && d <= RCRf) ? (0.5f*__cosf(((float)M_PI/RCRf)*d) + 0.5f) : 0.f;
            fca_v    = (!self && d <= RCAf) ? (0.5f*__cosf(((float)M_PI/RCAf)*d) + 0.5f) : 0.f;
            s_atom[tid] = make_float4(dx, dy, dz, d);
            s_dfr[tid]  = make_float2(d, fr);
            s_fca[tid]  = fca_v;
            s_sp[tid]   = species[n*NATOMS + tid];
        }
        unsigned long long m = __ballot(fca_v > 0.f);  // full-wave-active context
        if (fca_v > 0.f) s_nbr[__popcll(m & ((1ull << tid) - 1ull))] = tid;
        if (tid == 0) s_nn = (int)__popcll(m);
    }
    __syncthreads();                                   // barrier 1

    const int nn  = s_nn;
    const int cnt = (nn*(nn-1)) >> 1;
    const int M   = 2*nn - 1;

    // ---------- phase B: record at slot = p (no sorting) ----------
    const float CZ[8] = { 0.98078528f,  0.83146961f,  0.55557023f,  0.19509032f,
                         -0.19509032f, -0.55557023f, -0.83146961f, -0.98078528f};
    const float SZ[8] = { 0.19509032f,  0.55557023f,  0.83146961f,  0.98078528f,
                          0.98078528f,  0.83146961f,  0.55557023f,  0.19509032f};
    const float SHA[4] = {0.9f, 1.55f, 2.2f, 2.85f};

    #pragma unroll
    for (int rep = 0; rep < 2; ++rep) {
        int p = tid + rep*384;
        if (p < cnt) {
            // triangular decode in compacted space: off(x) = x*(2nn-x-1)/2
            float t = sqrtf((float)(M*M - 8*p));
            int jj = (int)(((float)M - t) * 0.5f);
            jj = max(0, min(jj, nn-2));
            while (jj*(2*nn-jj-1)/2 > p) --jj;          // <=2 fixup steps
            while ((jj+1)*(2*nn-jj-2)/2 <= p) ++jj;
            int kk = p - jj*(2*nn-jj-1)/2 + jj + 1;
            int j = s_nbr[jj], k = s_nbr[kk];
            float4 aj = s_atom[j], ak = s_atom[k];
            float fc2 = 2.f * s_fca[j] * s_fca[k];
            float dot = aj.x*ak.x + aj.y*ak.y + aj.z*ak.z;
            float c = 0.95f * dot * __builtin_amdgcn_rcpf(aj.w * ak.w);
            c = fminf(0.95f, fmaxf(-0.95f, c));
            float s = sqrtf(1.f - c*c);                 // sin(acos(c))
            float dmean = 0.5f * (aj.w + ak.w);
            int sj = s_sp[j], sk = s_sp[k];
            int lo = min(sj, sk), hi = max(sj, sk);
            float* r = &s_rec[p*12];
            float4 v0, v1, v2;
            v0.x = 0.5f + 0.5f*(c*CZ[0] + s*SZ[0]);
            v0.y = 0.5f + 0.5f*(c*CZ[1] + s*SZ[1]);
            v0.z = 0.5f + 0.5f*(c*CZ[2] + s*SZ[2]);
            v0.w = 0.5f + 0.5f*(c*CZ[3] + s*SZ[3]);
            v1.x = 0.5f + 0.5f*(c*CZ[4] + s*SZ[4]);
            v1.y = 0.5f + 0.5f*(c*CZ[5] + s*SZ[5]);
            v1.z = 0.5f + 0.5f*(c*CZ[6] + s*SZ[6]);
            v1.w = 0.5f + 0.5f*(c*CZ[7] + s*SZ[7]);
            #define POW32(q) { q = q*q; q = q*q; q = q*q; q = q*q; q = q*q; }
            POW32(v0.x) POW32(v0.y) POW32(v0.z) POW32(v0.w)
            POW32(v1.x) POW32(v1.y) POW32(v1.z) POW32(v1.w)
            #undef POW32
            float dm0 = dmean - SHA[0], dm1 = dmean - SHA[1];
            float dm2 = dmean - SHA[2], dm3 = dmean - SHA[3];
            v2.x = __expf(-8.f*dm0*dm0) * fc2;
            v2.y = __expf(-8.f*dm1*dm1) * fc2;
            v2.z = __expf(-8.f*dm2*dm2) * fc2;
            v2.w = __expf(-8.f*dm3*dm3) * fc2;
            *(float4*)(r+0) = v0;
            *(float4*)(r+4) = v1;
            *(float4*)(r+8) = v2;
            s_px[p] = ((lo*(9-lo)) >> 1) + (hi - lo);   // triu pair index, S=4
        }
    }
    __syncthreads();                                   // barrier 2

    // ---------- phase E ----------
    float* oa = out + NMOL*NATOMS + (size_t)bid * 384;

    if (tid < 320) {
        const int b = tid >> 5;
        const int a = (tid >> 3) & 3;
        const int z = tid & 7;
        float acc = 0.f;
        #pragma unroll 4
        for (int p = 0; p < cnt; ++p) {
            int   px = s_px[p];                        // b32 broadcast
            float f1 = s_rec[p*12 + z];                // 8 distinct banks
            float f2 = s_rec[p*12 + 8 + a];            // 4 distinct banks
            acc += (px == b) ? f1*f2 : 0.f;            // cndmask + fma, no branch
        }
        oa[64 + tid] = acc;
        if (tid == 0) out[bid] = (float)s_sp[i];       // output 0: species
    } else {
        const int f  = tid - 320;                      // 64 radial features
        const int rs = f >> 4;
        const float shr = 0.9f + 0.26875f * (float)(f & 15);   // SHF_R
        float racc = 0.f;
        #pragma unroll 8
        for (int j = 0; j < NATOMS; ++j) {
            float2 dfr = s_dfr[j];                     // fr==0 encodes mask
            float dmr = dfr.x - shr;
            racc += (s_sp[j] == rs) ? 0.25f * __expf(-16.f*dmr*dmr) * dfr.y : 0.f;
        }
        oa[f] = racc;
    }
}

extern "C" void kernel_launch(void* const* d_in, const int* in_sizes, int n_in,
                              void* d_out, int out_size, void* d_ws, size_t ws_size,
                              hipStream_t stream) {
    const int*   species = (const int*)d_in[0];
    const float* coords  = (const float*)d_in[1];
    float*       out     = (float*)d_out;
    aev_kernel<<<NMOL * NATOMS, 384, 0, stream>>>(species, coords, out);
}

// Round 9
// 18.522 us; speedup vs baseline: 1.1392x; 1.1392x over previous
//
#include <hip/hip_runtime.h>
#include <math.h>

#define NATOMS 32
#define NMOL   64
#define CAP    128     // records per chunk == one per thread
#define RCRf 5.2f
#define RCAf 3.5f

// One block per (molecule n, center atom i). 128 threads (2 waves) -> all 8
// blocks/CU co-resident in ONE dispatch round; barrier convoys idle at most
// one other wave. LDS ~9.5 KB.
// A (wave 0): per-atom dv/d/fc/species + ballot-compacted RCA neighbor list.
// Chunk loop (typical 1 iter; cnt>128 stragglers take 2-4):
//   B1: thread's pair p=ch*CAP+tid decoded in compacted space -> px, hist.
//   scan: 10 threads, exclusive prefix of bucket counts.
//   B2: factorized record {f1[0..7], f2f[0..3]} -> bucket-sorted slot (atomic).
//   E:  3 angular passes, feature (b,a,z) = f{tid, 128+tid, 256+tid}; each
//       scans only bucket b (2 LDS reads + fma per record), register acc.
// Radial: threads 64..127 own the 64 radial features (outside chunk loop).
__global__ __launch_bounds__(128) void aev_kernel(const int* __restrict__ species,
                                                  const float* __restrict__ coords,
                                                  float* __restrict__ out) {
    const int bid = blockIdx.x;
    const int n = bid >> 5;
    const int i = bid & 31;
    const int tid = threadIdx.x;

    __shared__ float4 s_atom[NATOMS];            // dvx, dvy, dvz, d
    __shared__ float2 s_dfr[NATOMS];             // d, fcr
    __shared__ float  s_fca[NATOMS];
    __shared__ int    s_sp[NATOMS];
    __shared__ int    s_nbr[NATOMS];
    __shared__ int    s_nn;
    __shared__ __align__(16) float s_rec[CAP*12];    // f1[0..7], f2f[0..3]
    __shared__ int    s_cnt[10], s_base[10], s_ofs[10];

    // ---------- phase A (wave 0) ----------
    if (tid < 64) {
        float fca_v = 0.f;
        if (tid < NATOMS) {
            const float* cb = coords + (size_t)n*NATOMS*3;
            float dx = cb[tid*3+0] - cb[i*3+0];
            float dy = cb[tid*3+1] - cb[i*3+1];
            float dz = cb[tid*3+2] - cb[i*3+2];
            float d2 = dx*dx + dy*dy + dz*dz;
            float d  = sqrtf(d2 > 0.f ? d2 : 1.f);   // ref's where(d2>0,d2,1) guard
            bool self = (tid == i);
            float fr = (!self && d <= RCRf) ? (0.5f*__cosf(((float)M_PI/RCRf)*d) + 0.5f) : 0.f;
            fca_v    = (!self && d <= RCAf) ? (0.5f*__cosf(((float)M_PI/RCAf)*d) + 0.5f) : 0.f;
            s_atom[tid] = make_float4(dx, dy, dz, d);
            s_dfr[tid]  = make_float2(d, fr);
            s_fca[tid]  = fca_v;
            s_sp[tid]   = species[n*NATOMS + tid];
        }
        unsigned long long m = __ballot(fca_v > 0.f);  // full-wave-active context
        if (fca_v > 0.f) s_nbr[__popcll(m & ((1ull << tid) - 1ull))] = tid;
        if (tid == 0) s_nn = (int)__popcll(m);
    }
    __syncthreads();

    const int nn  = s_nn;
    const int cnt = (nn*(nn-1)) >> 1;
    const int M   = 2*nn - 1;
    const int nchunks = (cnt + CAP - 1) / CAP;       // uniform across block

    const float CZ[8] = { 0.98078528f,  0.83146961f,  0.55557023f,  0.19509032f,
                         -0.19509032f, -0.55557023f, -0.83146961f, -0.98078528f};
    const float SZ[8] = { 0.19509032f,  0.55557023f,  0.83146961f,  0.98078528f,
                          0.98078528f,  0.83146961f,  0.55557023f,  0.19509032f};
    const float SHA[4] = {0.9f, 1.55f, 2.2f, 2.85f};

    float acc0 = 0.f, acc1 = 0.f, acc2 = 0.f;        // angular accumulators

    for (int ch = 0; ch < nchunks; ++ch) {
        __syncthreads();                             // prev E done / A visible
        if (tid < 10) s_cnt[tid] = 0;
        __syncthreads();

        // ---- B1: decode + histogram ----
        int j = -1, k = 0, px = 0;
        int p = ch*CAP + tid;
        if (p < cnt) {
            float t = sqrtf((float)(M*M - 8*p));
            int jj = (int)(((float)M - t) * 0.5f);
            jj = max(0, min(jj, nn-2));
            while (jj*(2*nn-jj-1)/2 > p) --jj;       // <=2 fixup steps
            while ((jj+1)*(2*nn-jj-2)/2 <= p) ++jj;
            int kk = p - jj*(2*nn-jj-1)/2 + jj + 1;
            j = s_nbr[jj]; k = s_nbr[kk];
            int sj = s_sp[j], sk = s_sp[k];
            int lo = min(sj, sk), hi = max(sj, sk);
            px = ((lo*(9-lo)) >> 1) + (hi - lo);     // triu pair index, S=4
            atomicAdd(&s_cnt[px], 1);
        }
        __syncthreads();

        // ---- scan: 10-thread exclusive prefix ----
        if (tid < 10) {
            int b = 0;
            for (int t = 0; t < tid; ++t) b += s_cnt[t];
            s_base[tid] = b; s_ofs[tid] = b;
        }
        __syncthreads();

        // ---- B2: factorized record -> bucket-sorted slot ----
        if (j >= 0) {
            float4 aj = s_atom[j], ak = s_atom[k];
            float fc2 = 2.f * s_fca[j] * s_fca[k];
            float dot = aj.x*ak.x + aj.y*ak.y + aj.z*ak.z;
            float c = 0.95f * dot * __builtin_amdgcn_rcpf(aj.w * ak.w);
            c = fminf(0.95f, fmaxf(-0.95f, c));
            float s = sqrtf(1.f - c*c);              // sin(acos(c))
            float dmean = 0.5f * (aj.w + ak.w);
            float4 v0, v1, v2;
            v0.x = 0.5f + 0.5f*(c*CZ[0] + s*SZ[0]);
            v0.y = 0.5f + 0.5f*(c*CZ[1] + s*SZ[1]);
            v0.z = 0.5f + 0.5f*(c*CZ[2] + s*SZ[2]);
            v0.w = 0.5f + 0.5f*(c*CZ[3] + s*SZ[3]);
            v1.x = 0.5f + 0.5f*(c*CZ[4] + s*SZ[4]);
            v1.y = 0.5f + 0.5f*(c*CZ[5] + s*SZ[5]);
            v1.z = 0.5f + 0.5f*(c*CZ[6] + s*SZ[6]);
            v1.w = 0.5f + 0.5f*(c*CZ[7] + s*SZ[7]);
            #define POW32(q) { q = q*q; q = q*q; q = q*q; q = q*q; q = q*q; }
            POW32(v0.x) POW32(v0.y) POW32(v0.z) POW32(v0.w)
            POW32(v1.x) POW32(v1.y) POW32(v1.z) POW32(v1.w)
            #undef POW32
            float dm0 = dmean - SHA[0], dm1 = dmean - SHA[1];
            float dm2 = dmean - SHA[2], dm3 = dmean - SHA[3];
            v2.x = __expf(-8.f*dm0*dm0) * fc2;
            v2.y = __expf(-8.f*dm1*dm1) * fc2;
            v2.z = __expf(-8.f*dm2*dm2) * fc2;
            v2.w = __expf(-8.f*dm3*dm3) * fc2;
            int slot = atomicAdd(&s_ofs[px], 1);
            float* r = &s_rec[slot*12];
            *(float4*)(r+0) = v0;
            *(float4*)(r+4) = v1;
            *(float4*)(r+8) = v2;
        }
        __syncthreads();

        // ---- E: 3 angular passes, bucket-scan only ----
        {
            int b0 = tid >> 5, a0 = (tid >> 3) & 3, z0 = tid & 7;
            int q0 = s_base[b0], q0e = q0 + s_cnt[b0];
            #pragma unroll 2
            for (int q = q0; q < q0e; ++q)
                acc0 += s_rec[q*12 + z0] * s_rec[q*12 + 8 + a0];
            int f = 128 + tid;
            int b1 = f >> 5, a1 = (f >> 3) & 3, z1 = f & 7;
            int q1 = s_base[b1], q1e = q1 + s_cnt[b1];
            #pragma unroll 2
            for (int q = q1; q < q1e; ++q)
                acc1 += s_rec[q*12 + z1] * s_rec[q*12 + 8 + a1];
            if (tid < 64) {
                int g = 256 + tid;
                int b2 = g >> 5, a2 = (g >> 3) & 3, z2 = g & 7;
                int q2 = s_base[b2], q2e = q2 + s_cnt[b2];
                #pragma unroll 2
                for (int q = q2; q < q2e; ++q)
                    acc2 += s_rec[q*12 + z2] * s_rec[q*12 + 8 + a2];
            }
        }
    }

    // ---------- radial (threads 64..127) + writes ----------
    float* oa = out + NMOL*NATOMS + (size_t)bid * 384;
    oa[64 + tid]  = acc0;
    oa[192 + tid] = acc1;
    if (tid < 64) oa[320 + tid] = acc2;
    else {
        const int f  = tid - 64;
        const int rs = f >> 4;
        const float shr = 0.9f + 0.26875f * (float)(f & 15);   // SHF_R
        float racc = 0.f;
        #pragma unroll 4
        for (int jj = 0; jj < NATOMS; ++jj) {
            float2 dfr = s_dfr[jj];                  // fr==0 encodes mask
            float dmr = dfr.x - shr;
            racc += (s_sp[jj] == rs) ? 0.25f * __expf(-16.f*dmr*dmr) * dfr.y : 0.f;
        }
        oa[f] = racc;
    }
    if (tid == 0) out[bid] = (float)s_sp[i];         // output 0: species
}

extern "C" void kernel_launch(void* const* d_in, const int* in_sizes, int n_in,
                              void* d_out, int out_size, void* d_ws, size_t ws_size,
                              hipStream_t stream) {
    const int*   species = (const int*)d_in[0];
    const float* coords  = (const float*)d_in[1];
    float*       out     = (float*)d_out;
    aev_kernel<<<NMOL * NATOMS, 128, 0, stream>>>(species, coords, out);
}